// Round 18
// baseline (3248.285 us; speedup 1.0000x reference)
//
#include <hip/hip_runtime.h>
#include <stdint.h>

constexpr int Cc   = 256;
constexpr int Kc   = 1024;
constexpr int NLOC = 16 * 56 * 56;      // 50176
constexpr int NB   = 2;
constexpr int NTOT = NB * NLOC;         // 100352
constexpr long long ZQV = (long long)NB * Cc * NLOC;  // 25690112

// screen tiling (R14/R16/R17-validated geometry)
constexpr int SR   = 128;
constexpr int SC   = 128;
constexpr int BK   = 64;
constexpr int NCH  = Cc / BK;           // 4
constexpr int NRT  = NTOT / SR;         // 784 row tiles (= 8 XCDs x 98)
constexpr int NSL  = Kc / SC;           // 8
constexpr int SBLK = NRT * NSL;         // 6272

constexpr int   SPS  = 4;               // candidate slots per (row, slice)
constexpr float WIN  = 3e-4f;           // validated
constexpr float NEG2S = -0.001953125f;  // -2/1024 (exact descale)

constexpr int F1B = NTOT / 256;         // 392
constexpr int RB  = 32;                 // rows per gather block
constexpr int F2B = NTOT / RB;          // 3136

using f16x8 = __attribute__((ext_vector_type(8))) _Float16;
using f32x4 = __attribute__((ext_vector_type(4))) float;
typedef unsigned long long u64;
typedef unsigned int       u32;
typedef unsigned short     u16;

// ---------------------------------------------------------------------------
// numpy-exact helpers (validated, unchanged)
// ---------------------------------------------------------------------------
__device__ __forceinline__ float sqf(float x) {
    float s = x * x;
    asm("" : "+v"(s));
    return s;
}

template <typename Loader>
__device__ __forceinline__ float pw128_sq(Loader ld)
{
    float r[8];
    #pragma unroll
    for (int j = 0; j < 8; ++j) r[j] = sqf(ld(j));
    #pragma unroll
    for (int i = 8; i < 128; i += 8)
        #pragma unroll
        for (int j = 0; j < 8; ++j) r[j] += sqf(ld(i + j));
    return ((r[0] + r[1]) + (r[2] + r[3])) + ((r[4] + r[5]) + (r[6] + r[7]));
}

template <typename Loader>
__device__ __forceinline__ float pw256_sq(Loader ld)
{
    float h0 = pw128_sq([&](int c) { return ld(c); });
    float h1 = pw128_sq([&](int c) { return ld(128 + c); });
    return h0 + h1;
}

__device__ __forceinline__ u16 f16b(float x)
{
    _Float16 h = (_Float16)x;   // v_cvt_f16_f32, RNE
    u16 r;
    __builtin_memcpy(&r, &h, 2);
    return r;
}

// ---------------------------------------------------------------------------
// prep_key: split_e + esq + cntg zeroing (grid covers NTOT*NSL)
// ---------------------------------------------------------------------------
__global__ void prep_key(const float* __restrict__ key, u16* __restrict__ ef16,
                         float* __restrict__ esq,
                         int* __restrict__ cntg, int* __restrict__ wcount)
{
    int i = blockIdx.x * 256 + threadIdx.x;
    if (i < Kc * Cc) ef16[i] = f16b(key[i] * 1024.0f);
    if (i < NTOT * NSL) cntg[i] = 0;
    if (i == 0) *wcount = 0;
    if (i < Kc) {
        const float* a = key + (size_t)i * Cc;
        esq[i] = pw256_sq([&](int c) { return a[c]; });
    }
}

// ---------------------------------------------------------------------------
// split_z: two 128-c halves (R17-validated: 33.8 KB LDS, 4 blocks/CU)
// ---------------------------------------------------------------------------
__global__ __launch_bounds__(256, 4)
void split_z(const float* __restrict__ z, u16* __restrict__ zf16,
             float* __restrict__ zt32, float* __restrict__ zsq)
{
    __shared__ float t[64][132];
    const int tid = threadIdx.x;
    const int n0  = blockIdx.x * 64;
    const int b   = (n0 >= NLOC) ? 1 : 0;
    const int loc0 = n0 - b * NLOC;
    const float* zb = z + (size_t)b * Cc * NLOC;

    float hs0 = 0.f;

    #pragma unroll
    for (int h = 0; h < 2; ++h) {
        if (h) __syncthreads();
        {
            const int n4 = tid & 15;
            #pragma unroll
            for (int it = 0; it < 2; ++it) {
                int c4 = (tid >> 4) + it * 16;
                int cg = h * 128 + c4 * 4;
                float4 g0 = *reinterpret_cast<const float4*>(zb + (size_t)(cg + 0) * NLOC + loc0 + n4 * 4);
                float4 g1 = *reinterpret_cast<const float4*>(zb + (size_t)(cg + 1) * NLOC + loc0 + n4 * 4);
                float4 g2 = *reinterpret_cast<const float4*>(zb + (size_t)(cg + 2) * NLOC + loc0 + n4 * 4);
                float4 g3 = *reinterpret_cast<const float4*>(zb + (size_t)(cg + 3) * NLOC + loc0 + n4 * 4);
                *reinterpret_cast<float4*>(&t[n4 * 4 + 0][c4 * 4]) = make_float4(g0.x, g1.x, g2.x, g3.x);
                *reinterpret_cast<float4*>(&t[n4 * 4 + 1][c4 * 4]) = make_float4(g0.y, g1.y, g2.y, g3.y);
                *reinterpret_cast<float4*>(&t[n4 * 4 + 2][c4 * 4]) = make_float4(g0.z, g1.z, g2.z, g3.z);
                *reinterpret_cast<float4*>(&t[n4 * 4 + 3][c4 * 4]) = make_float4(g0.w, g1.w, g2.w, g3.w);
            }
        }
        __syncthreads();
        {
            const int row2 = tid >> 4;
            const int ch   = tid & 15;
            #pragma unroll
            for (int rg = 0; rg < 4; ++rg) {
                int row = rg * 16 + row2;
                float4 f0 = *reinterpret_cast<const float4*>(&t[row][ch * 8]);
                float4 f1 = *reinterpret_cast<const float4*>(&t[row][ch * 8 + 4]);
                float xs[8] = {f0.x, f0.y, f0.z, f0.w, f1.x, f1.y, f1.z, f1.w};
                u32 hp[4];
                #pragma unroll
                for (int j = 0; j < 4; ++j)
                    hp[j] = (u32)f16b(xs[2 * j]) | ((u32)f16b(xs[2 * j + 1]) << 16);
                size_t o = ((size_t)(n0 + row)) * Cc + h * 128 + ch * 8;
                *reinterpret_cast<uint4*>(zf16 + o) = make_uint4(hp[0], hp[1], hp[2], hp[3]);
                if (zt32) {
                    *reinterpret_cast<float4*>(zt32 + o)     = f0;
                    *reinterpret_cast<float4*>(zt32 + o + 4) = f1;
                }
            }
        }
        if (tid < 64) {
            float hv = pw128_sq([&](int c) { return t[tid][c]; });
            if (h == 0) hs0 = hv;
            else        zsq[n0 + tid] = hs0 + hv;
        }
    }
}

// global -> LDS direct, 16B/lane
__device__ __forceinline__ void gload16(const u16* g, u16* lds)
{
    __builtin_amdgcn_global_load_lds(
        (const __attribute__((address_space(1))) u32*)g,
        (__attribute__((address_space(3))) u32*)lds, 16, 0, 0);
}

// ---------------------------------------------------------------------------
// screen: R16/R17 GEMM core; NEW emission: LDS counters + block-private
// cand regions [row][slice][SPS] — zero global atomics.
// ---------------------------------------------------------------------------
__global__ __launch_bounds__(256, 4)
void screen(const u16* __restrict__ zf16, const u16* __restrict__ ef16,
            const float* __restrict__ esq, const float* __restrict__ zsq,
            u64* __restrict__ cand, int* __restrict__ cntg)
{
    __shared__ u16  A_lds[SR * BK];    // 16 KB
    __shared__ u16  B_lds[SC * BK];    // 16 KB
    __shared__ float gm[2][SR];        // 1 KB
    __shared__ float esq_s[SC];
    __shared__ float zsq_s[SR];
    __shared__ int   lcnt[SR];         // per-row LDS emission counters

    const int tid = threadIdx.x;
    const int bid = blockIdx.x;
    const int q   = bid >> 3;
    const int rt  = (bid & 7) * (NRT / 8) + (q >> 3);
    const int r0  = rt * SR;
    const int slice = q & 7;
    const int k0  = slice * SC;
    const int wid = tid >> 6, l = tid & 63;
    const int wr  = wid >> 1, wc = wid & 1;

    for (int i = tid; i < SC; i += 256) esq_s[i] = esq[k0 + i];
    for (int i = tid; i < SR; i += 256) { zsq_s[i] = zsq[r0 + i]; lcnt[i] = 0; }

    f32x4 acc[4][4];
    #pragma unroll
    for (int i = 0; i < 4; ++i)
        #pragma unroll
        for (int j = 0; j < 4; ++j)
            acc[i][j] = f32x4{0.f, 0.f, 0.f, 0.f};

    for (int ch = 0; ch < NCH; ++ch) {
        __syncthreads();
        {
            const int lr = l >> 3;
            #pragma unroll
            for (int t = 0; t < 4; ++t) {
                int rowb = wid * 32 + t * 8;
                int row  = rowb + lr;
                int g    = (l & 7) ^ (row & 7);
                gload16(zf16 + (size_t)(r0 + row) * Cc + ch * BK + g * 8,
                        A_lds + rowb * BK);
                gload16(ef16 + (size_t)(k0 + row) * Cc + ch * BK + g * 8,
                        B_lds + rowb * BK);
            }
        }
        __syncthreads();

        #pragma unroll
        for (int kk = 0; kk < 2; ++kk) {
            f16x8 af[4], bf[4];
            const int G = kk * 4 + (l >> 4);
            #pragma unroll
            for (int i = 0; i < 4; ++i) {
                int row = wr * 64 + i * 16 + (l & 15);
                int pg  = G ^ (row & 7);
                af[i] = *reinterpret_cast<const f16x8*>(&A_lds[row * BK + pg * 8]);
            }
            #pragma unroll
            for (int j = 0; j < 4; ++j) {
                int col = wc * 64 + j * 16 + (l & 15);
                int pg  = G ^ (col & 7);
                bf[j] = *reinterpret_cast<const f16x8*>(&B_lds[col * BK + pg * 8]);
            }
            #pragma unroll
            for (int i = 0; i < 4; ++i)
                #pragma unroll
                for (int j = 0; j < 4; ++j)
                    acc[i][j] = __builtin_amdgcn_mfma_f32_16x16x32_f16(
                        af[i], bf[j], acc[i][j], 0, 0, 0);
        }
    }

    // ---- epilogue pass 1: f32 slice-min per row ----
    #pragma unroll
    for (int i = 0; i < 4; ++i) {
        #pragma unroll
        for (int r = 0; r < 4; ++r) {
            int rloc = wr * 64 + i * 16 + ((l >> 4) << 2) + r;
            float zq = zsq_s[rloc];
            float mn = 3.4e38f;
            #pragma unroll
            for (int j = 0; j < 4; ++j) {
                int cl = wc * 64 + j * 16 + (l & 15);
                float d = fmaf(NEG2S, acc[i][j][r], zq + esq_s[cl]);
                mn = fminf(mn, d);
            }
            #pragma unroll
            for (int m = 1; m < 16; m <<= 1)
                mn = fminf(mn, __shfl_xor(mn, m, 64));
            if ((l & 15) == 0) gm[wc][rloc] = mn;
        }
    }
    __syncthreads();

    // ---- epilogue pass 2: window emission via LDS counters ----
    #pragma unroll
    for (int i = 0; i < 4; ++i) {
        #pragma unroll
        for (int r = 0; r < 4; ++r) {
            int rloc = wr * 64 + i * 16 + ((l >> 4) << 2) + r;
            float thr = fminf(gm[0][rloc], gm[1][rloc]) + WIN;
            float zq = zsq_s[rloc];
            #pragma unroll
            for (int j = 0; j < 4; ++j) {
                int cl = wc * 64 + j * 16 + (l & 15);
                float d = fmaf(NEG2S, acc[i][j][r], zq + esq_s[cl]);
                if (d <= thr) {
                    int slot = atomicAdd(&lcnt[rloc], 1);   // LDS atomic (~5 cyc)
                    if (slot < SPS)
                        cand[((size_t)(r0 + rloc) * NSL + slice) * SPS + slot] =
                            ((u64)__float_as_uint(d) << 32) | (u32)(k0 + cl);
                }
            }
        }
    }
    __syncthreads();
    // write per-(row, slice) counts (plain stores — block owns this region)
    for (int i = tid; i < SR; i += 256)
        cntg[(r0 + i) * NSL + slice] = lcnt[i];
}

// ---------------------------------------------------------------------------
// resolve_pick: scan all 8 slices' candidate sets; overflow/ambiguous -> wl.
// ---------------------------------------------------------------------------
__global__ __launch_bounds__(256)
void resolve_pick(const u64* __restrict__ cand, const int* __restrict__ cntg,
                  int* __restrict__ idxw, float* __restrict__ dbest,
                  float* __restrict__ out,
                  int* __restrict__ wl, int* __restrict__ wcount)
{
    const int p = blockIdx.x * 256 + threadIdx.x;
    u64 best = 0xFFFFFFFFFFFFFFFFull;
    bool ovf = false;
    #pragma unroll
    for (int s = 0; s < NSL; ++s) {
        int c = cntg[p * NSL + s];
        ovf |= (c > SPS);
        int n = c < SPS ? c : SPS;
        for (int t = 0; t < n; ++t) {
            u64 v = cand[((size_t)p * NSL + s) * SPS + t];
            if (v < best) best = v;
        }
    }
    const float db = __uint_as_float((u32)(best >> 32));

    bool needs = ovf;
    if (!needs) {
        int namb = 0;
        #pragma unroll
        for (int s = 0; s < NSL; ++s) {
            int n = cntg[p * NSL + s];
            n = n < SPS ? n : SPS;
            for (int t = 0; t < n; ++t) {
                float dv = __uint_as_float(
                    (u32)(cand[((size_t)p * NSL + s) * SPS + t] >> 32));
                namb += (dv <= db + WIN) ? 1 : 0;
            }
        }
        needs = (namb > 1);
    }
    if (needs) wl[atomicAdd(wcount, 1)] = p;

    idxw[p] = (int)(u32)best;
    dbest[p] = db;
    out[ZQV + p] = (float)(u32)best;
}

// ---------------------------------------------------------------------------
// rescore: np-exact re-evaluation of worklist rows (contiguous zt32 rows).
// ---------------------------------------------------------------------------
__global__ __launch_bounds__(256)
void rescore(const float* __restrict__ zt32, const float* __restrict__ key,
             const float* __restrict__ esq, const float* __restrict__ zsq,
             const u64* __restrict__ cand, const int* __restrict__ cntg,
             const int* __restrict__ wcount, const int* __restrict__ wl,
             int* __restrict__ idxw, float* __restrict__ dbest,
             float* __restrict__ out)
{
    const int i = blockIdx.x * 256 + threadIdx.x;
    if (i >= *wcount) return;
    const int p = wl[i];
    const float* zr = zt32 + (size_t)p * Cc;
    const float zq = zsq[p];

    bool ovf = false;
    #pragma unroll
    for (int s = 0; s < NSL; ++s) ovf |= (cntg[p * NSL + s] > SPS);

    u64 bb = 0xFFFFFFFFFFFFFFFFull;
    if (ovf) {
        // full np-exact scan
        for (int k = 0; k < Kc; ++k) {
            const float* kr = key + (size_t)k * Cc;
            float m = 0.f;
            for (int cc = 0; cc < Cc; ++cc)
                m = fmaf(zr[cc], kr[cc], m);
            float d = fmaf(-2.0f, m, zq + esq[k]);
            u64 pk = ((u64)__float_as_uint(d) << 32) | (u32)k;
            if (pk < bb) bb = pk;
        }
    } else {
        u64 best = 0xFFFFFFFFFFFFFFFFull;
        #pragma unroll
        for (int s = 0; s < NSL; ++s) {
            int n = cntg[p * NSL + s];
            n = n < SPS ? n : SPS;
            for (int t = 0; t < n; ++t) {
                u64 v = cand[((size_t)p * NSL + s) * SPS + t];
                if (v < best) best = v;
            }
        }
        const float db = __uint_as_float((u32)(best >> 32));
        #pragma unroll
        for (int s = 0; s < NSL; ++s) {
            int n = cntg[p * NSL + s];
            n = n < SPS ? n : SPS;
            for (int t = 0; t < n; ++t) {
                u64 v = cand[((size_t)p * NSL + s) * SPS + t];
                float dv = __uint_as_float((u32)(v >> 32));
                if (dv <= db + WIN) {
                    int k = (int)(u32)v;
                    const float* kr = key + (size_t)k * Cc;
                    float m = 0.f;
                    for (int cc = 0; cc < Cc; ++cc)
                        m = fmaf(zr[cc], kr[cc], m);
                    float d = fmaf(-2.0f, m, zq + esq[k]);
                    u64 pk = ((u64)__float_as_uint(d) << 32) | (u32)k;
                    if (pk < bb) bb = pk;
                }
            }
        }
    }
    idxw[p] = (int)(u32)bb;
    dbest[p] = __uint_as_float((u32)(bb >> 32));
    out[ZQV + p] = (float)(u32)bb;
}

// ---------------------------------------------------------------------------
// resolve_fallback: monolithic path (strided z reads) if ws too small for zt32
// ---------------------------------------------------------------------------
__global__ __launch_bounds__(256)
void resolve_fallback(const float* __restrict__ z, const float* __restrict__ key,
                      const float* __restrict__ esq, const float* __restrict__ zsq,
                      const u64* __restrict__ cand, const int* __restrict__ cntg,
                      float* __restrict__ out, int* __restrict__ idxw,
                      float* __restrict__ dbest)
{
    const int p   = blockIdx.x * 256 + threadIdx.x;
    const int b   = (p >= NLOC) ? 1 : 0;
    const int loc = p - b * NLOC;
    const float* zb = z + (size_t)b * Cc * NLOC;

    u64 best = 0xFFFFFFFFFFFFFFFFull;
    bool ovf = false;
    #pragma unroll
    for (int s = 0; s < NSL; ++s) {
        int c = cntg[p * NSL + s];
        ovf |= (c > SPS);
        int n = c < SPS ? c : SPS;
        for (int t = 0; t < n; ++t) {
            u64 v = cand[((size_t)p * NSL + s) * SPS + t];
            if (v < best) best = v;
        }
    }
    u64 sel = best;
    const float db = __uint_as_float((u32)(best >> 32));

    bool needs = ovf;
    if (!needs) {
        int namb = 0;
        #pragma unroll
        for (int s = 0; s < NSL; ++s) {
            int n = cntg[p * NSL + s];
            n = n < SPS ? n : SPS;
            for (int t = 0; t < n; ++t) {
                float dv = __uint_as_float(
                    (u32)(cand[((size_t)p * NSL + s) * SPS + t] >> 32));
                namb += (dv <= db + WIN) ? 1 : 0;
            }
        }
        needs = (namb > 1);
    }

    if (ovf) {
        u64 bb = 0xFFFFFFFFFFFFFFFFull;
        for (int k = 0; k < Kc; ++k) {
            const float* kr = key + (size_t)k * Cc;
            float m = 0.f;
            for (int cc = 0; cc < Cc; ++cc)
                m = fmaf(zb[(size_t)cc * NLOC + loc], kr[cc], m);
            float d = fmaf(-2.0f, m, zsq[p] + esq[k]);
            u64 pk = ((u64)__float_as_uint(d) << 32) | (u32)k;
            if (pk < bb) bb = pk;
        }
        sel = bb;
    } else if (needs) {
        u64 bb = 0xFFFFFFFFFFFFFFFFull;
        #pragma unroll
        for (int s = 0; s < NSL; ++s) {
            int n = cntg[p * NSL + s];
            n = n < SPS ? n : SPS;
            for (int t = 0; t < n; ++t) {
                u64 v = cand[((size_t)p * NSL + s) * SPS + t];
                float dv = __uint_as_float((u32)(v >> 32));
                if (dv <= db + WIN) {
                    int k = (int)(u32)v;
                    const float* kr = key + (size_t)k * Cc;
                    float m = 0.f;
                    for (int cc = 0; cc < Cc; ++cc)
                        m = fmaf(zb[(size_t)cc * NLOC + loc], kr[cc], m);
                    float d = fmaf(-2.0f, m, zsq[p] + esq[k]);
                    u64 pk = ((u64)__float_as_uint(d) << 32) | (u32)k;
                    if (pk < bb) bb = pk;
                }
            }
        }
        sel = bb;
    }
    idxw[p] = (int)(u32)sel;
    dbest[p] = __uint_as_float((u32)(sel >> 32));
    out[ZQV + p] = (float)(u32)sel;
}

// ---------------------------------------------------------------------------
// gather: val-row gather + z_q_value write + fused dbest partial.
// ---------------------------------------------------------------------------
__global__ __launch_bounds__(256)
void gather(const float* __restrict__ val, const int* __restrict__ idxw,
            const float* __restrict__ dbest,
            float* __restrict__ out, double* __restrict__ partial)
{
    __shared__ float rowbuf[RB][261];
    __shared__ int   idx_sh[RB];
    const int tid = threadIdx.x, blk = blockIdx.x;
    const int wid = tid >> 6, l = tid & 63;
    const int p0  = blk * RB;
    const int b   = (p0 >= NLOC) ? 1 : 0;
    const int loc0 = p0 - b * NLOC;

    if (tid < RB) idx_sh[tid] = idxw[p0 + tid];

    if (tid < 64) {
        double s = (tid < RB) ? (double)dbest[p0 + tid] : 0.0;
        for (int off = 32; off > 0; off >>= 1) s += __shfl_down(s, off);
        if (tid == 0) partial[blk] = s;
    }
    __syncthreads();

    #pragma unroll
    for (int i = 0; i < RB / 4; ++i) {
        int row = wid * (RB / 4) + i;
        float4 v = *reinterpret_cast<const float4*>(val + (size_t)idx_sh[row] * Cc + l * 4);
        *reinterpret_cast<float4*>(&rowbuf[row][l * 4]) = v;
    }
    __syncthreads();

    const int nq = l & 7;
    #pragma unroll
    for (int it = 0; it < 8; ++it) {
        int cc = (l >> 3) + 8 * it + 64 * wid;
        float4 v = make_float4(rowbuf[nq * 4 + 0][cc], rowbuf[nq * 4 + 1][cc],
                               rowbuf[nq * 4 + 2][cc], rowbuf[nq * 4 + 3][cc]);
        *reinterpret_cast<float4*>(
            out + ((size_t)b * Cc + cc) * NLOC + loc0 + nq * 4) = v;
    }
}

__global__ void fin_kernel(const double* __restrict__ partial, float* __restrict__ out_loss)
{
    __shared__ double sh[256];
    double s = 0.0;
    for (int i = threadIdx.x; i < F2B; i += 256) s += partial[i];
    sh[threadIdx.x] = s;
    __syncthreads();
    for (int st = 128; st > 0; st >>= 1) {
        if (threadIdx.x < st) sh[threadIdx.x] += sh[threadIdx.x + st];
        __syncthreads();
    }
    if (threadIdx.x == 0)
        out_loss[0] = (float)(1.25 * sh[0] / (double)((long long)NTOT * Cc));
}

// ---------------------------------------------------------------------------
extern "C" void kernel_launch(void* const* d_in, const int* in_sizes, int n_in,
                              void* d_out, int out_size, void* d_ws, size_t ws_size,
                              hipStream_t stream)
{
    const float* z   = (const float*)d_in[0];
    const float* key = (const float*)d_in[1];
    const float* val = (const float*)d_in[2];
    float* out = (float*)d_out;

    u16* zf16 = (u16*)d_out;   // dead before gather overwrites

    char* w = (char*)d_ws;
    u16*    ef16    = (u16*)w;                 w += (size_t)Kc * Cc * 2;             // 512 KB
    u64*    cand    = (u64*)w;                 w += (size_t)NTOT * NSL * SPS * 8;    // 25.7 MB
    int*    cntg    = (int*)w;                 w += (size_t)NTOT * NSL * 4;          // 3.2 MB
    int*    wcount  = (int*)w;                 w += 16;
    int*    idxw    = (int*)w;                 w += (size_t)NTOT * 4;
    int*    wl      = (int*)w;                 w += (size_t)NTOT * 4;
    float*  dbest   = (float*)w;               w += (size_t)NTOT * 4;
    double* partial = (double*)w;              w += (size_t)F2B * 8;
    float*  esq     = (float*)w;               w += (size_t)Kc * 4;
    float*  zsq     = (float*)w;               w += (size_t)NTOT * 4;
    float*  zt32    = (float*)w;
    size_t  need_big = (size_t)(w - (char*)d_ws) + (size_t)NTOT * Cc * 4;
    const bool big = ws_size >= need_big;

    hipLaunchKernelGGL(prep_key, dim3((NTOT * NSL + 255) / 256), dim3(256), 0, stream,
                       key, ef16, esq, cntg, wcount);
    hipLaunchKernelGGL(split_z, dim3(NTOT / 64), dim3(256), 0, stream, z, zf16,
                       big ? zt32 : (float*)nullptr, zsq);
    hipLaunchKernelGGL(screen, dim3(SBLK), dim3(256), 0, stream,
                       zf16, ef16, esq, zsq, cand, cntg);
    if (big) {
        hipLaunchKernelGGL(resolve_pick, dim3(F1B), dim3(256), 0, stream,
                           cand, cntg, idxw, dbest, out, wl, wcount);
        hipLaunchKernelGGL(rescore, dim3(F1B), dim3(256), 0, stream,
                           zt32, key, esq, zsq, cand, cntg, wcount, wl, idxw, dbest, out);
    } else {
        hipLaunchKernelGGL(resolve_fallback, dim3(F1B), dim3(256), 0, stream,
                           z, key, esq, zsq, cand, cntg, out, idxw, dbest);
    }
    hipLaunchKernelGGL(gather, dim3(F2B), dim3(256), 0, stream,
                       val, idxw, dbest, out, partial);
    hipLaunchKernelGGL(fin_kernel, dim3(1), dim3(256), 0, stream, partial, out + ZQV + NTOT);
}

// Round 20
// 306.331 us; speedup vs baseline: 10.6038x; 10.6038x over previous
//
#include <hip/hip_runtime.h>
#include <stdint.h>

constexpr int Cc   = 256;
constexpr int Kc   = 1024;
constexpr int NLOC = 16 * 56 * 56;      // 50176
constexpr int NB   = 2;
constexpr int NTOT = NB * NLOC;         // 100352
constexpr long long ZQV = (long long)NB * Cc * NLOC;  // 25690112

// screen tiling (R14-R19-validated geometry)
constexpr int SR   = 128;
constexpr int SC   = 128;
constexpr int BK   = 64;
constexpr int NCH  = Cc / BK;           // 4
constexpr int NRT  = NTOT / SR;         // 784 row tiles (= 8 XCDs x 98)
constexpr int NSL  = Kc / SC;           // 8
constexpr int SBLK = NRT * NSL;         // 6272

constexpr int   SPS   = 4;              // candidate slots per (row, slice)
constexpr float WIN   = 3e-4f;          // emission window (validated)
constexpr float HMARG = 2e-4f;          // ambiguity/harmful margin (~18 sigma)
constexpr float NEG2S = -0.001953125f;  // -2/1024 (exact descale)

constexpr int F1B  = NTOT / 256;        // 392
constexpr int RB   = 32;                // rows per gather block
constexpr int F2B  = NTOT / RB;         // 3136
constexpr int RPB2 = 256;               // rows owned per rescore_ovf block
constexpr int OVB  = NTOT / RPB2;       // 392

using f16x8 = __attribute__((ext_vector_type(8))) _Float16;
using f32x4 = __attribute__((ext_vector_type(4))) float;
typedef unsigned long long u64;
typedef unsigned int       u32;
typedef unsigned short     u16;

// ---------------------------------------------------------------------------
// numpy-exact helpers (validated, unchanged)
// ---------------------------------------------------------------------------
__device__ __forceinline__ float sqf(float x) {
    float s = x * x;
    asm("" : "+v"(s));
    return s;
}

template <typename Loader>
__device__ __forceinline__ float pw128_sq(Loader ld)
{
    float r[8];
    #pragma unroll
    for (int j = 0; j < 8; ++j) r[j] = sqf(ld(j));
    #pragma unroll
    for (int i = 8; i < 128; i += 8)
        #pragma unroll
        for (int j = 0; j < 8; ++j) r[j] += sqf(ld(i + j));
    return ((r[0] + r[1]) + (r[2] + r[3])) + ((r[4] + r[5]) + (r[6] + r[7]));
}

template <typename Loader>
__device__ __forceinline__ float pw256_sq(Loader ld)
{
    float h0 = pw128_sq([&](int c) { return ld(c); });
    float h1 = pw128_sq([&](int c) { return ld(128 + c); });
    return h0 + h1;
}

__device__ __forceinline__ u16 f16b(float x)
{
    _Float16 h = (_Float16)x;   // v_cvt_f16_f32, RNE
    u16 r;
    __builtin_memcpy(&r, &h, 2);
    return r;
}

// ---------------------------------------------------------------------------
// prep_key: split_e + esq + cntg zeroing (grid covers NTOT*NSL)
// ---------------------------------------------------------------------------
__global__ void prep_key(const float* __restrict__ key, u16* __restrict__ ef16,
                         float* __restrict__ esq, int* __restrict__ cntg)
{
    int i = blockIdx.x * 256 + threadIdx.x;
    if (i < Kc * Cc) ef16[i] = f16b(key[i] * 1024.0f);
    if (i < NTOT * NSL) cntg[i] = 0;
    if (i < Kc) {
        const float* a = key + (size_t)i * Cc;
        esq[i] = pw256_sq([&](int c) { return a[c]; });
    }
}

// ---------------------------------------------------------------------------
// split_z: two 128-c halves (R17-validated: 33.8 KB LDS, 4 blocks/CU)
// ---------------------------------------------------------------------------
__global__ __launch_bounds__(256, 4)
void split_z(const float* __restrict__ z, u16* __restrict__ zf16,
             float* __restrict__ zt32, float* __restrict__ zsq)
{
    __shared__ float t[64][132];
    const int tid = threadIdx.x;
    const int n0  = blockIdx.x * 64;
    const int b   = (n0 >= NLOC) ? 1 : 0;
    const int loc0 = n0 - b * NLOC;
    const float* zb = z + (size_t)b * Cc * NLOC;

    float hs0 = 0.f;

    #pragma unroll
    for (int h = 0; h < 2; ++h) {
        if (h) __syncthreads();
        {
            const int n4 = tid & 15;
            #pragma unroll
            for (int it = 0; it < 2; ++it) {
                int c4 = (tid >> 4) + it * 16;
                int cg = h * 128 + c4 * 4;
                float4 g0 = *reinterpret_cast<const float4*>(zb + (size_t)(cg + 0) * NLOC + loc0 + n4 * 4);
                float4 g1 = *reinterpret_cast<const float4*>(zb + (size_t)(cg + 1) * NLOC + loc0 + n4 * 4);
                float4 g2 = *reinterpret_cast<const float4*>(zb + (size_t)(cg + 2) * NLOC + loc0 + n4 * 4);
                float4 g3 = *reinterpret_cast<const float4*>(zb + (size_t)(cg + 3) * NLOC + loc0 + n4 * 4);
                *reinterpret_cast<float4*>(&t[n4 * 4 + 0][c4 * 4]) = make_float4(g0.x, g1.x, g2.x, g3.x);
                *reinterpret_cast<float4*>(&t[n4 * 4 + 1][c4 * 4]) = make_float4(g0.y, g1.y, g2.y, g3.y);
                *reinterpret_cast<float4*>(&t[n4 * 4 + 2][c4 * 4]) = make_float4(g0.z, g1.z, g2.z, g3.z);
                *reinterpret_cast<float4*>(&t[n4 * 4 + 3][c4 * 4]) = make_float4(g0.w, g1.w, g2.w, g3.w);
            }
        }
        __syncthreads();
        {
            const int row2 = tid >> 4;
            const int ch   = tid & 15;
            #pragma unroll
            for (int rg = 0; rg < 4; ++rg) {
                int row = rg * 16 + row2;
                float4 f0 = *reinterpret_cast<const float4*>(&t[row][ch * 8]);
                float4 f1 = *reinterpret_cast<const float4*>(&t[row][ch * 8 + 4]);
                float xs[8] = {f0.x, f0.y, f0.z, f0.w, f1.x, f1.y, f1.z, f1.w};
                u32 hp[4];
                #pragma unroll
                for (int j = 0; j < 4; ++j)
                    hp[j] = (u32)f16b(xs[2 * j]) | ((u32)f16b(xs[2 * j + 1]) << 16);
                size_t o = ((size_t)(n0 + row)) * Cc + h * 128 + ch * 8;
                *reinterpret_cast<uint4*>(zf16 + o) = make_uint4(hp[0], hp[1], hp[2], hp[3]);
                if (zt32) {
                    *reinterpret_cast<float4*>(zt32 + o)     = f0;
                    *reinterpret_cast<float4*>(zt32 + o + 4) = f1;
                }
            }
        }
        if (tid < 64) {
            float hv = pw128_sq([&](int c) { return t[tid][c]; });
            if (h == 0) hs0 = hv;
            else        zsq[n0 + tid] = hs0 + hv;
        }
    }
}

// global -> LDS direct, 16B/lane
__device__ __forceinline__ void gload16(const u16* g, u16* lds)
{
    __builtin_amdgcn_global_load_lds(
        (const __attribute__((address_space(1))) u32*)g,
        (__attribute__((address_space(3))) u32*)lds, 16, 0, 0);
}

// ---------------------------------------------------------------------------
// screen: R18-validated GEMM + LDS-counter emission; NEW: deterministic
// per-(row,slice) minimum stored to smin[].
// ---------------------------------------------------------------------------
__global__ __launch_bounds__(256, 4)
void screen(const u16* __restrict__ zf16, const u16* __restrict__ ef16,
            const float* __restrict__ esq, const float* __restrict__ zsq,
            u64* __restrict__ cand, int* __restrict__ cntg,
            float* __restrict__ smin)
{
    __shared__ u16  A_lds[SR * BK];    // 16 KB
    __shared__ u16  B_lds[SC * BK];    // 16 KB
    __shared__ float gm[2][SR];        // 1 KB
    __shared__ float esq_s[SC];
    __shared__ float zsq_s[SR];
    __shared__ int   lcnt[SR];

    const int tid = threadIdx.x;
    const int bid = blockIdx.x;
    const int q   = bid >> 3;
    const int rt  = (bid & 7) * (NRT / 8) + (q >> 3);
    const int r0  = rt * SR;
    const int slice = q & 7;
    const int k0  = slice * SC;
    const int wid = tid >> 6, l = tid & 63;
    const int wr  = wid >> 1, wc = wid & 1;

    for (int i = tid; i < SC; i += 256) esq_s[i] = esq[k0 + i];
    for (int i = tid; i < SR; i += 256) { zsq_s[i] = zsq[r0 + i]; lcnt[i] = 0; }

    f32x4 acc[4][4];
    #pragma unroll
    for (int i = 0; i < 4; ++i)
        #pragma unroll
        for (int j = 0; j < 4; ++j)
            acc[i][j] = f32x4{0.f, 0.f, 0.f, 0.f};

    for (int ch = 0; ch < NCH; ++ch) {
        __syncthreads();
        {
            const int lr = l >> 3;
            #pragma unroll
            for (int t = 0; t < 4; ++t) {
                int rowb = wid * 32 + t * 8;
                int row  = rowb + lr;
                int g    = (l & 7) ^ (row & 7);
                gload16(zf16 + (size_t)(r0 + row) * Cc + ch * BK + g * 8,
                        A_lds + rowb * BK);
                gload16(ef16 + (size_t)(k0 + row) * Cc + ch * BK + g * 8,
                        B_lds + rowb * BK);
            }
        }
        __syncthreads();

        #pragma unroll
        for (int kk = 0; kk < 2; ++kk) {
            f16x8 af[4], bf[4];
            const int G = kk * 4 + (l >> 4);
            #pragma unroll
            for (int i = 0; i < 4; ++i) {
                int row = wr * 64 + i * 16 + (l & 15);
                int pg  = G ^ (row & 7);
                af[i] = *reinterpret_cast<const f16x8*>(&A_lds[row * BK + pg * 8]);
            }
            #pragma unroll
            for (int j = 0; j < 4; ++j) {
                int col = wc * 64 + j * 16 + (l & 15);
                int pg  = G ^ (col & 7);
                bf[j] = *reinterpret_cast<const f16x8*>(&B_lds[col * BK + pg * 8]);
            }
            #pragma unroll
            for (int i = 0; i < 4; ++i)
                #pragma unroll
                for (int j = 0; j < 4; ++j)
                    acc[i][j] = __builtin_amdgcn_mfma_f32_16x16x32_f16(
                        af[i], bf[j], acc[i][j], 0, 0, 0);
        }
    }

    // ---- epilogue pass 1: f32 slice-min per row (deterministic order) ----
    #pragma unroll
    for (int i = 0; i < 4; ++i) {
        #pragma unroll
        for (int r = 0; r < 4; ++r) {
            int rloc = wr * 64 + i * 16 + ((l >> 4) << 2) + r;
            float zq = zsq_s[rloc];
            float mn = 3.4e38f;
            #pragma unroll
            for (int j = 0; j < 4; ++j) {
                int cl = wc * 64 + j * 16 + (l & 15);
                float d = fmaf(NEG2S, acc[i][j][r], zq + esq_s[cl]);
                mn = fminf(mn, d);
            }
            #pragma unroll
            for (int m = 1; m < 16; m <<= 1)
                mn = fminf(mn, __shfl_xor(mn, m, 64));
            if ((l & 15) == 0) gm[wc][rloc] = mn;
        }
    }
    __syncthreads();

    // deterministic slice-min store
    for (int i = tid; i < SR; i += 256)
        smin[(size_t)(r0 + i) * NSL + slice] = fminf(gm[0][i], gm[1][i]);

    // ---- epilogue pass 2: window emission via LDS counters ----
    #pragma unroll
    for (int i = 0; i < 4; ++i) {
        #pragma unroll
        for (int r = 0; r < 4; ++r) {
            int rloc = wr * 64 + i * 16 + ((l >> 4) << 2) + r;
            float thr = fminf(gm[0][rloc], gm[1][rloc]) + WIN;
            float zq = zsq_s[rloc];
            #pragma unroll
            for (int j = 0; j < 4; ++j) {
                int cl = wc * 64 + j * 16 + (l & 15);
                float d = fmaf(NEG2S, acc[i][j][r], zq + esq_s[cl]);
                if (d <= thr) {
                    int slot = atomicAdd(&lcnt[rloc], 1);   // LDS atomic
                    if (slot < SPS)
                        cand[((size_t)(r0 + rloc) * NSL + slice) * SPS + slot] =
                            ((u64)__float_as_uint(d) << 32) | (u32)(k0 + cl);
                }
            }
        }
    }
    __syncthreads();
    for (int i = tid; i < SR; i += 256)
        cntg[(size_t)(r0 + i) * NSL + slice] = lcnt[i];
}

// ---------------------------------------------------------------------------
// resolve_pick: fully deterministic classification via smin (no atomics,
// no worklists). Writes outputs ONLY for need==0 rows (single-writer).
//   need=2: some slice overflows AND its min is within HMARG of global min
//           (only then could a dropped candidate matter) -> full rescan.
//   need=1: >1 stored candidates within HMARG of global min -> np rescore.
//   need=0: unique winner -> final.
// ---------------------------------------------------------------------------
__global__ __launch_bounds__(256)
void resolve_pick(const u64* __restrict__ cand, const int* __restrict__ cntg,
                  const float* __restrict__ smin, int* __restrict__ need,
                  int* __restrict__ idxw, float* __restrict__ dbest,
                  float* __restrict__ out)
{
    const int p = blockIdx.x * 256 + threadIdx.x;

    float dbg = 3.4e38f;
    #pragma unroll
    for (int s = 0; s < NSL; ++s) dbg = fminf(dbg, smin[(size_t)p * NSL + s]);

    bool harmful = false;
    #pragma unroll
    for (int s = 0; s < NSL; ++s) {
        int c = cntg[(size_t)p * NSL + s];
        harmful |= (c > SPS) && (smin[(size_t)p * NSL + s] <= dbg + HMARG);
    }
    if (harmful) { need[p] = 2; return; }

    u64 best = 0xFFFFFFFFFFFFFFFFull;
    int namb = 0;
    #pragma unroll
    for (int s = 0; s < NSL; ++s) {
        int c = cntg[(size_t)p * NSL + s];
        int n = c < SPS ? c : SPS;
        for (int t = 0; t < n; ++t) {
            u64 v = cand[((size_t)p * NSL + s) * SPS + t];
            if (v < best) best = v;
            float dv = __uint_as_float((u32)(v >> 32));
            namb += (dv <= dbg + HMARG) ? 1 : 0;
        }
    }
    if (namb > 1) { need[p] = 1; return; }

    need[p] = 0;
    idxw[p]  = (int)(u32)best;
    dbest[p] = __uint_as_float((u32)(best >> 32));
    out[ZQV + p] = (float)(u32)best;
}

// ---------------------------------------------------------------------------
// rescore_amb: sole writer for need==1 rows — np-exact rescore of the
// deterministic contender set (all stored; dv <= dbg + HMARG).
// ---------------------------------------------------------------------------
__global__ __launch_bounds__(256)
void rescore_amb(const float* __restrict__ zt32, const float* __restrict__ key,
                 const float* __restrict__ esq, const float* __restrict__ zsq,
                 const u64* __restrict__ cand, const int* __restrict__ cntg,
                 const float* __restrict__ smin, const int* __restrict__ need,
                 int* __restrict__ idxw, float* __restrict__ dbest,
                 float* __restrict__ out)
{
    const int p = blockIdx.x * 256 + threadIdx.x;
    if (need[p] != 1) return;
    const float* zr = zt32 + (size_t)p * Cc;
    const float zq = zsq[p];

    float dbg = 3.4e38f;
    #pragma unroll
    for (int s = 0; s < NSL; ++s) dbg = fminf(dbg, smin[(size_t)p * NSL + s]);

    u64 bb = 0xFFFFFFFFFFFFFFFFull;
    #pragma unroll
    for (int s = 0; s < NSL; ++s) {
        int c = cntg[(size_t)p * NSL + s];
        int n = c < SPS ? c : SPS;
        for (int t = 0; t < n; ++t) {
            u64 v = cand[((size_t)p * NSL + s) * SPS + t];
            float dv = __uint_as_float((u32)(v >> 32));
            if (dv <= dbg + HMARG) {
                int k = (int)(u32)v;
                const float* kr = key + (size_t)k * Cc;
                float m = 0.f;
                for (int cc = 0; cc < Cc; ++cc)
                    m = fmaf(zr[cc], kr[cc], m);
                float d = fmaf(-2.0f, m, zq + esq[k]);
                u64 pk = ((u64)__float_as_uint(d) << 32) | (u32)k;
                if (pk < bb) bb = pk;
            }
        }
    }
    idxw[p]  = (int)(u32)bb;
    dbest[p] = __uint_as_float((u32)(bb >> 32));
    out[ZQV + p] = (float)(u32)bb;
}

// ---------------------------------------------------------------------------
// rescore_ovf: sole writer for need==2 rows. Block b owns rows
// [b*RPB2, (b+1)*RPB2); block-parallel np-exact full scan per flagged row.
// ---------------------------------------------------------------------------
__global__ __launch_bounds__(256)
void rescore_ovf(const float* __restrict__ zt32, const float* __restrict__ key,
                 const float* __restrict__ esq, const float* __restrict__ zsq,
                 const int* __restrict__ need,
                 int* __restrict__ idxw, float* __restrict__ dbest,
                 float* __restrict__ out)
{
    __shared__ float zr_s[Cc];
    __shared__ u64 wred[4];
    const int tid = threadIdx.x;

    for (int rr = 0; rr < RPB2; ++rr) {
        const int p = blockIdx.x * RPB2 + rr;
        if (need[p] != 2) continue;          // uniform across block

        __syncthreads();                     // prior row's zr_s readers done
        zr_s[tid] = zt32[(size_t)p * Cc + tid];
        __syncthreads();
        const float zq = zsq[p];

        float a0 = 0.f, a1 = 0.f, a2 = 0.f, a3 = 0.f;
        const float* kr0 = key + (size_t)(tid +   0) * Cc;
        const float* kr1 = key + (size_t)(tid + 256) * Cc;
        const float* kr2 = key + (size_t)(tid + 512) * Cc;
        const float* kr3 = key + (size_t)(tid + 768) * Cc;
        for (int cc = 0; cc < Cc; ++cc) {
            float zv = zr_s[cc];
            a0 = fmaf(zv, kr0[cc], a0);
            a1 = fmaf(zv, kr1[cc], a1);
            a2 = fmaf(zv, kr2[cc], a2);
            a3 = fmaf(zv, kr3[cc], a3);
        }
        u64 mn = 0xFFFFFFFFFFFFFFFFull;
        float av[4] = {a0, a1, a2, a3};
        #pragma unroll
        for (int g = 0; g < 4; ++g) {
            int k = tid + 256 * g;
            float d = fmaf(-2.0f, av[g], zq + esq[k]);
            u64 pk = ((u64)__float_as_uint(d) << 32) | (u32)k;
            mn = pk < mn ? pk : mn;
        }
        #pragma unroll
        for (int m = 1; m < 64; m <<= 1) {
            u64 o = __shfl_xor(mn, m, 64);
            mn = o < mn ? o : mn;
        }
        if ((tid & 63) == 0) wred[tid >> 6] = mn;
        __syncthreads();
        if (tid == 0) {
            u64 bsel = wred[0];
            #pragma unroll
            for (int i2 = 1; i2 < 4; ++i2) bsel = wred[i2] < bsel ? wred[i2] : bsel;
            idxw[p]  = (int)(u32)bsel;
            dbest[p] = __uint_as_float((u32)(bsel >> 32));
            out[ZQV + p] = (float)(u32)bsel;
        }
    }
}

// ---------------------------------------------------------------------------
// resolve_fallback (!big): monolithic deterministic path with strided z.
// ---------------------------------------------------------------------------
__global__ __launch_bounds__(256)
void resolve_fallback(const float* __restrict__ z, const float* __restrict__ key,
                      const float* __restrict__ esq, const float* __restrict__ zsq,
                      const u64* __restrict__ cand, const int* __restrict__ cntg,
                      const float* __restrict__ smin,
                      float* __restrict__ out, int* __restrict__ idxw,
                      float* __restrict__ dbest)
{
    const int p   = blockIdx.x * 256 + threadIdx.x;
    const int b   = (p >= NLOC) ? 1 : 0;
    const int loc = p - b * NLOC;
    const float* zb = z + (size_t)b * Cc * NLOC;

    float dbg = 3.4e38f;
    #pragma unroll
    for (int s = 0; s < NSL; ++s) dbg = fminf(dbg, smin[(size_t)p * NSL + s]);
    bool harmful = false;
    #pragma unroll
    for (int s = 0; s < NSL; ++s) {
        int c = cntg[(size_t)p * NSL + s];
        harmful |= (c > SPS) && (smin[(size_t)p * NSL + s] <= dbg + HMARG);
    }

    u64 sel = 0xFFFFFFFFFFFFFFFFull;
    if (harmful) {
        for (int k = 0; k < Kc; ++k) {
            const float* kr = key + (size_t)k * Cc;
            float m = 0.f;
            for (int cc = 0; cc < Cc; ++cc)
                m = fmaf(zb[(size_t)cc * NLOC + loc], kr[cc], m);
            float d = fmaf(-2.0f, m, zsq[p] + esq[k]);
            u64 pk = ((u64)__float_as_uint(d) << 32) | (u32)k;
            if (pk < sel) sel = pk;
        }
    } else {
        u64 best = 0xFFFFFFFFFFFFFFFFull;
        int namb = 0;
        #pragma unroll
        for (int s = 0; s < NSL; ++s) {
            int c = cntg[(size_t)p * NSL + s];
            int n = c < SPS ? c : SPS;
            for (int t = 0; t < n; ++t) {
                u64 v = cand[((size_t)p * NSL + s) * SPS + t];
                if (v < best) best = v;
                float dv = __uint_as_float((u32)(v >> 32));
                namb += (dv <= dbg + HMARG) ? 1 : 0;
            }
        }
        sel = best;
        if (namb > 1) {
            u64 bb = 0xFFFFFFFFFFFFFFFFull;
            #pragma unroll
            for (int s = 0; s < NSL; ++s) {
                int c = cntg[(size_t)p * NSL + s];
                int n = c < SPS ? c : SPS;
                for (int t = 0; t < n; ++t) {
                    u64 v = cand[((size_t)p * NSL + s) * SPS + t];
                    float dv = __uint_as_float((u32)(v >> 32));
                    if (dv <= dbg + HMARG) {
                        int k = (int)(u32)v;
                        const float* kr = key + (size_t)k * Cc;
                        float m = 0.f;
                        for (int cc = 0; cc < Cc; ++cc)
                            m = fmaf(zb[(size_t)cc * NLOC + loc], kr[cc], m);
                        float d = fmaf(-2.0f, m, zsq[p] + esq[k]);
                        u64 pk = ((u64)__float_as_uint(d) << 32) | (u32)k;
                        if (pk < bb) bb = pk;
                    }
                }
            }
            sel = bb;
        }
    }
    idxw[p]  = (int)(u32)sel;
    dbest[p] = __uint_as_float((u32)(sel >> 32));
    out[ZQV + p] = (float)(u32)sel;
}

// ---------------------------------------------------------------------------
// gather: val-row gather + z_q_value write + fused dbest partial.
// ---------------------------------------------------------------------------
__global__ __launch_bounds__(256)
void gather(const float* __restrict__ val, const int* __restrict__ idxw,
            const float* __restrict__ dbest,
            float* __restrict__ out, double* __restrict__ partial)
{
    __shared__ float rowbuf[RB][261];
    __shared__ int   idx_sh[RB];
    const int tid = threadIdx.x, blk = blockIdx.x;
    const int wid = tid >> 6, l = tid & 63;
    const int p0  = blk * RB;
    const int b   = (p0 >= NLOC) ? 1 : 0;
    const int loc0 = p0 - b * NLOC;

    if (tid < RB) idx_sh[tid] = idxw[p0 + tid];

    if (tid < 64) {
        double s = (tid < RB) ? (double)dbest[p0 + tid] : 0.0;
        for (int off = 32; off > 0; off >>= 1) s += __shfl_down(s, off);
        if (tid == 0) partial[blk] = s;
    }
    __syncthreads();

    #pragma unroll
    for (int i = 0; i < RB / 4; ++i) {
        int row = wid * (RB / 4) + i;
        float4 v = *reinterpret_cast<const float4*>(val + (size_t)idx_sh[row] * Cc + l * 4);
        *reinterpret_cast<float4*>(&rowbuf[row][l * 4]) = v;
    }
    __syncthreads();

    const int nq = l & 7;
    #pragma unroll
    for (int it = 0; it < 8; ++it) {
        int cc = (l >> 3) + 8 * it + 64 * wid;
        float4 v = make_float4(rowbuf[nq * 4 + 0][cc], rowbuf[nq * 4 + 1][cc],
                               rowbuf[nq * 4 + 2][cc], rowbuf[nq * 4 + 3][cc]);
        *reinterpret_cast<float4*>(
            out + ((size_t)b * Cc + cc) * NLOC + loc0 + nq * 4) = v;
    }
}

__global__ void fin_kernel(const double* __restrict__ partial, float* __restrict__ out_loss)
{
    __shared__ double sh[256];
    double s = 0.0;
    for (int i = threadIdx.x; i < F2B; i += 256) s += partial[i];
    sh[threadIdx.x] = s;
    __syncthreads();
    for (int st = 128; st > 0; st >>= 1) {
        if (threadIdx.x < st) sh[threadIdx.x] += sh[threadIdx.x + st];
        __syncthreads();
    }
    if (threadIdx.x == 0)
        out_loss[0] = (float)(1.25 * sh[0] / (double)((long long)NTOT * Cc));
}

// ---------------------------------------------------------------------------
extern "C" void kernel_launch(void* const* d_in, const int* in_sizes, int n_in,
                              void* d_out, int out_size, void* d_ws, size_t ws_size,
                              hipStream_t stream)
{
    const float* z   = (const float*)d_in[0];
    const float* key = (const float*)d_in[1];
    const float* val = (const float*)d_in[2];
    float* out = (float*)d_out;

    u16* zf16 = (u16*)d_out;   // dead before gather overwrites

    char* w = (char*)d_ws;
    u16*    ef16    = (u16*)w;                 w += (size_t)Kc * Cc * 2;             // 512 KB
    u64*    cand    = (u64*)w;                 w += (size_t)NTOT * NSL * SPS * 8;    // 25.7 MB
    int*    cntg    = (int*)w;                 w += (size_t)NTOT * NSL * 4;          // 3.2 MB
    float*  smin    = (float*)w;               w += (size_t)NTOT * NSL * 4;          // 3.2 MB
    int*    need    = (int*)w;                 w += (size_t)NTOT * 4;
    int*    idxw    = (int*)w;                 w += (size_t)NTOT * 4;
    float*  dbest   = (float*)w;               w += (size_t)NTOT * 4;
    double* partial = (double*)w;              w += (size_t)F2B * 8;
    float*  esq     = (float*)w;               w += (size_t)Kc * 4;
    float*  zsq     = (float*)w;               w += (size_t)NTOT * 4;
    float*  zt32    = (float*)w;
    size_t  need_big = (size_t)(w - (char*)d_ws) + (size_t)NTOT * Cc * 4;
    const bool big = ws_size >= need_big;

    hipLaunchKernelGGL(prep_key, dim3((NTOT * NSL + 255) / 256), dim3(256), 0, stream,
                       key, ef16, esq, cntg);
    hipLaunchKernelGGL(split_z, dim3(NTOT / 64), dim3(256), 0, stream, z, zf16,
                       big ? zt32 : (float*)nullptr, zsq);
    hipLaunchKernelGGL(screen, dim3(SBLK), dim3(256), 0, stream,
                       zf16, ef16, esq, zsq, cand, cntg, smin);
    if (big) {
        hipLaunchKernelGGL(resolve_pick, dim3(F1B), dim3(256), 0, stream,
                           cand, cntg, smin, need, idxw, dbest, out);
        hipLaunchKernelGGL(rescore_amb, dim3(F1B), dim3(256), 0, stream,
                           zt32, key, esq, zsq, cand, cntg, smin, need, idxw, dbest, out);
        hipLaunchKernelGGL(rescore_ovf, dim3(OVB), dim3(256), 0, stream,
                           zt32, key, esq, zsq, need, idxw, dbest, out);
    } else {
        hipLaunchKernelGGL(resolve_fallback, dim3(F1B), dim3(256), 0, stream,
                           z, key, esq, zsq, cand, cntg, smin, out, idxw, dbest);
    }
    hipLaunchKernelGGL(gather, dim3(F2B), dim3(256), 0, stream,
                       val, idxw, dbest, out, partial);
    hipLaunchKernelGGL(fin_kernel, dim3(1), dim3(256), 0, stream, partial, out + ZQV + NTOT);
}

// Round 21
// 305.798 us; speedup vs baseline: 10.6223x; 1.0017x over previous
//
#include <hip/hip_runtime.h>
#include <stdint.h>

constexpr int Cc   = 256;
constexpr int Kc   = 1024;
constexpr int NLOC = 16 * 56 * 56;      // 50176
constexpr int NB   = 2;
constexpr int NTOT = NB * NLOC;         // 100352
constexpr long long ZQV = (long long)NB * Cc * NLOC;  // 25690112

// screen tiling (R14-R20-validated geometry)
constexpr int SR   = 128;
constexpr int SC   = 128;
constexpr int BK   = 64;
constexpr int NCH  = Cc / BK;           // 4
constexpr int NRT  = NTOT / SR;         // 784 row tiles (= 8 XCDs x 98)
constexpr int NSL  = Kc / SC;           // 8
constexpr int SBLK = NRT * NSL;         // 6272

constexpr int   SPS   = 4;              // candidate slots per (row, slice)
constexpr float WIN   = 3e-4f;          // emission window (validated)
constexpr float HMARG = 2e-4f;          // ambiguity/harmful margin (~18 sigma)
constexpr float NEG2S = -0.001953125f;  // -2/1024 (exact descale)

constexpr int F1B  = NTOT / 256;        // 392
constexpr int RB   = 32;                // rows per gather block
constexpr int F2B  = NTOT / RB;         // 3136
constexpr int RPB2 = 256;               // rows owned per rescore_ovf block
constexpr int OVB  = NTOT / RPB2;       // 392

using f16x8 = __attribute__((ext_vector_type(8))) _Float16;
using f32x4 = __attribute__((ext_vector_type(4))) float;
typedef unsigned long long u64;
typedef unsigned int       u32;
typedef unsigned short     u16;

// ---------------------------------------------------------------------------
// numpy-exact helpers (validated, unchanged)
// ---------------------------------------------------------------------------
__device__ __forceinline__ float sqf(float x) {
    float s = x * x;
    asm("" : "+v"(s));
    return s;
}

template <typename Loader>
__device__ __forceinline__ float pw128_sq(Loader ld)
{
    float r[8];
    #pragma unroll
    for (int j = 0; j < 8; ++j) r[j] = sqf(ld(j));
    #pragma unroll
    for (int i = 8; i < 128; i += 8)
        #pragma unroll
        for (int j = 0; j < 8; ++j) r[j] += sqf(ld(i + j));
    return ((r[0] + r[1]) + (r[2] + r[3])) + ((r[4] + r[5]) + (r[6] + r[7]));
}

template <typename Loader>
__device__ __forceinline__ float pw256_sq(Loader ld)
{
    float h0 = pw128_sq([&](int c) { return ld(c); });
    float h1 = pw128_sq([&](int c) { return ld(128 + c); });
    return h0 + h1;
}

__device__ __forceinline__ u16 f16b(float x)
{
    _Float16 h = (_Float16)x;   // v_cvt_f16_f32, RNE
    u16 r;
    __builtin_memcpy(&r, &h, 2);
    return r;
}

// ---------------------------------------------------------------------------
// prep_key: split_e + esq. (cntg zeroing REMOVED — screen unconditionally
// writes every (row, slice) count, so initialization is redundant.)
// ---------------------------------------------------------------------------
__global__ void prep_key(const float* __restrict__ key, u16* __restrict__ ef16,
                         float* __restrict__ esq)
{
    int i = blockIdx.x * 256 + threadIdx.x;
    if (i < Kc * Cc) ef16[i] = f16b(key[i] * 1024.0f);
    if (i < Kc) {
        const float* a = key + (size_t)i * Cc;
        esq[i] = pw256_sq([&](int c) { return a[c]; });
    }
}

// ---------------------------------------------------------------------------
// split_z: two 128-c halves (R17-validated: 33.8 KB LDS, 4 blocks/CU)
// ---------------------------------------------------------------------------
__global__ __launch_bounds__(256, 4)
void split_z(const float* __restrict__ z, u16* __restrict__ zf16,
             float* __restrict__ zt32, float* __restrict__ zsq)
{
    __shared__ float t[64][132];
    const int tid = threadIdx.x;
    const int n0  = blockIdx.x * 64;
    const int b   = (n0 >= NLOC) ? 1 : 0;
    const int loc0 = n0 - b * NLOC;
    const float* zb = z + (size_t)b * Cc * NLOC;

    float hs0 = 0.f;

    #pragma unroll
    for (int h = 0; h < 2; ++h) {
        if (h) __syncthreads();
        {
            const int n4 = tid & 15;
            #pragma unroll
            for (int it = 0; it < 2; ++it) {
                int c4 = (tid >> 4) + it * 16;
                int cg = h * 128 + c4 * 4;
                float4 g0 = *reinterpret_cast<const float4*>(zb + (size_t)(cg + 0) * NLOC + loc0 + n4 * 4);
                float4 g1 = *reinterpret_cast<const float4*>(zb + (size_t)(cg + 1) * NLOC + loc0 + n4 * 4);
                float4 g2 = *reinterpret_cast<const float4*>(zb + (size_t)(cg + 2) * NLOC + loc0 + n4 * 4);
                float4 g3 = *reinterpret_cast<const float4*>(zb + (size_t)(cg + 3) * NLOC + loc0 + n4 * 4);
                *reinterpret_cast<float4*>(&t[n4 * 4 + 0][c4 * 4]) = make_float4(g0.x, g1.x, g2.x, g3.x);
                *reinterpret_cast<float4*>(&t[n4 * 4 + 1][c4 * 4]) = make_float4(g0.y, g1.y, g2.y, g3.y);
                *reinterpret_cast<float4*>(&t[n4 * 4 + 2][c4 * 4]) = make_float4(g0.z, g1.z, g2.z, g3.z);
                *reinterpret_cast<float4*>(&t[n4 * 4 + 3][c4 * 4]) = make_float4(g0.w, g1.w, g2.w, g3.w);
            }
        }
        __syncthreads();
        {
            const int row2 = tid >> 4;
            const int ch   = tid & 15;
            #pragma unroll
            for (int rg = 0; rg < 4; ++rg) {
                int row = rg * 16 + row2;
                float4 f0 = *reinterpret_cast<const float4*>(&t[row][ch * 8]);
                float4 f1 = *reinterpret_cast<const float4*>(&t[row][ch * 8 + 4]);
                float xs[8] = {f0.x, f0.y, f0.z, f0.w, f1.x, f1.y, f1.z, f1.w};
                u32 hp[4];
                #pragma unroll
                for (int j = 0; j < 4; ++j)
                    hp[j] = (u32)f16b(xs[2 * j]) | ((u32)f16b(xs[2 * j + 1]) << 16);
                size_t o = ((size_t)(n0 + row)) * Cc + h * 128 + ch * 8;
                *reinterpret_cast<uint4*>(zf16 + o) = make_uint4(hp[0], hp[1], hp[2], hp[3]);
                if (zt32) {
                    *reinterpret_cast<float4*>(zt32 + o)     = f0;
                    *reinterpret_cast<float4*>(zt32 + o + 4) = f1;
                }
            }
        }
        if (tid < 64) {
            float hv = pw128_sq([&](int c) { return t[tid][c]; });
            if (h == 0) hs0 = hv;
            else        zsq[n0 + tid] = hs0 + hv;
        }
    }
}

// global -> LDS direct, 16B/lane
__device__ __forceinline__ void gload16(const u16* g, u16* lds)
{
    __builtin_amdgcn_global_load_lds(
        (const __attribute__((address_space(1))) u32*)g,
        (__attribute__((address_space(3))) u32*)lds, 16, 0, 0);
}

// ---------------------------------------------------------------------------
// screen: R20-validated — GEMM + LDS-counter emission + deterministic smin.
// ---------------------------------------------------------------------------
__global__ __launch_bounds__(256, 4)
void screen(const u16* __restrict__ zf16, const u16* __restrict__ ef16,
            const float* __restrict__ esq, const float* __restrict__ zsq,
            u64* __restrict__ cand, int* __restrict__ cntg,
            float* __restrict__ smin)
{
    __shared__ u16  A_lds[SR * BK];    // 16 KB
    __shared__ u16  B_lds[SC * BK];    // 16 KB
    __shared__ float gm[2][SR];        // 1 KB
    __shared__ float esq_s[SC];
    __shared__ float zsq_s[SR];
    __shared__ int   lcnt[SR];

    const int tid = threadIdx.x;
    const int bid = blockIdx.x;
    const int q   = bid >> 3;
    const int rt  = (bid & 7) * (NRT / 8) + (q >> 3);
    const int r0  = rt * SR;
    const int slice = q & 7;
    const int k0  = slice * SC;
    const int wid = tid >> 6, l = tid & 63;
    const int wr  = wid >> 1, wc = wid & 1;

    for (int i = tid; i < SC; i += 256) esq_s[i] = esq[k0 + i];
    for (int i = tid; i < SR; i += 256) { zsq_s[i] = zsq[r0 + i]; lcnt[i] = 0; }

    f32x4 acc[4][4];
    #pragma unroll
    for (int i = 0; i < 4; ++i)
        #pragma unroll
        for (int j = 0; j < 4; ++j)
            acc[i][j] = f32x4{0.f, 0.f, 0.f, 0.f};

    for (int ch = 0; ch < NCH; ++ch) {
        __syncthreads();
        {
            const int lr = l >> 3;
            #pragma unroll
            for (int t = 0; t < 4; ++t) {
                int rowb = wid * 32 + t * 8;
                int row  = rowb + lr;
                int g    = (l & 7) ^ (row & 7);
                gload16(zf16 + (size_t)(r0 + row) * Cc + ch * BK + g * 8,
                        A_lds + rowb * BK);
                gload16(ef16 + (size_t)(k0 + row) * Cc + ch * BK + g * 8,
                        B_lds + rowb * BK);
            }
        }
        __syncthreads();

        #pragma unroll
        for (int kk = 0; kk < 2; ++kk) {
            f16x8 af[4], bf[4];
            const int G = kk * 4 + (l >> 4);
            #pragma unroll
            for (int i = 0; i < 4; ++i) {
                int row = wr * 64 + i * 16 + (l & 15);
                int pg  = G ^ (row & 7);
                af[i] = *reinterpret_cast<const f16x8*>(&A_lds[row * BK + pg * 8]);
            }
            #pragma unroll
            for (int j = 0; j < 4; ++j) {
                int col = wc * 64 + j * 16 + (l & 15);
                int pg  = G ^ (col & 7);
                bf[j] = *reinterpret_cast<const f16x8*>(&B_lds[col * BK + pg * 8]);
            }
            #pragma unroll
            for (int i = 0; i < 4; ++i)
                #pragma unroll
                for (int j = 0; j < 4; ++j)
                    acc[i][j] = __builtin_amdgcn_mfma_f32_16x16x32_f16(
                        af[i], bf[j], acc[i][j], 0, 0, 0);
        }
    }

    // ---- epilogue pass 1: f32 slice-min per row (deterministic order) ----
    #pragma unroll
    for (int i = 0; i < 4; ++i) {
        #pragma unroll
        for (int r = 0; r < 4; ++r) {
            int rloc = wr * 64 + i * 16 + ((l >> 4) << 2) + r;
            float zq = zsq_s[rloc];
            float mn = 3.4e38f;
            #pragma unroll
            for (int j = 0; j < 4; ++j) {
                int cl = wc * 64 + j * 16 + (l & 15);
                float d = fmaf(NEG2S, acc[i][j][r], zq + esq_s[cl]);
                mn = fminf(mn, d);
            }
            #pragma unroll
            for (int m = 1; m < 16; m <<= 1)
                mn = fminf(mn, __shfl_xor(mn, m, 64));
            if ((l & 15) == 0) gm[wc][rloc] = mn;
        }
    }
    __syncthreads();

    // deterministic slice-min store
    for (int i = tid; i < SR; i += 256)
        smin[(size_t)(r0 + i) * NSL + slice] = fminf(gm[0][i], gm[1][i]);

    // ---- epilogue pass 2: window emission via LDS counters ----
    #pragma unroll
    for (int i = 0; i < 4; ++i) {
        #pragma unroll
        for (int r = 0; r < 4; ++r) {
            int rloc = wr * 64 + i * 16 + ((l >> 4) << 2) + r;
            float thr = fminf(gm[0][rloc], gm[1][rloc]) + WIN;
            float zq = zsq_s[rloc];
            #pragma unroll
            for (int j = 0; j < 4; ++j) {
                int cl = wc * 64 + j * 16 + (l & 15);
                float d = fmaf(NEG2S, acc[i][j][r], zq + esq_s[cl]);
                if (d <= thr) {
                    int slot = atomicAdd(&lcnt[rloc], 1);   // LDS atomic
                    if (slot < SPS)
                        cand[((size_t)(r0 + rloc) * NSL + slice) * SPS + slot] =
                            ((u64)__float_as_uint(d) << 32) | (u32)(k0 + cl);
                }
            }
        }
    }
    __syncthreads();
    for (int i = tid; i < SR; i += 256)
        cntg[(size_t)(r0 + i) * NSL + slice] = lcnt[i];
}

// ---------------------------------------------------------------------------
// resolve: FUSED resolve_pick + rescore_amb (deterministic, no atomics).
//   need=2: harmful overflow -> flagged for rescore_ovf (no output writes).
//   need=1: ambiguous -> inline np-exact rescore of contender set (all stored).
//   need=0: unique winner -> final.
// Sole writer of outputs for need in {0,1}; rescore_ovf for need==2.
// ---------------------------------------------------------------------------
__global__ __launch_bounds__(256)
void resolve(const float* __restrict__ zt32, const float* __restrict__ key,
             const float* __restrict__ esq, const float* __restrict__ zsq,
             const u64* __restrict__ cand, const int* __restrict__ cntg,
             const float* __restrict__ smin, int* __restrict__ need,
             int* __restrict__ idxw, float* __restrict__ dbest,
             float* __restrict__ out)
{
    const int p = blockIdx.x * 256 + threadIdx.x;

    float dbg = 3.4e38f;
    #pragma unroll
    for (int s = 0; s < NSL; ++s) dbg = fminf(dbg, smin[(size_t)p * NSL + s]);

    bool harmful = false;
    #pragma unroll
    for (int s = 0; s < NSL; ++s) {
        int c = cntg[(size_t)p * NSL + s];
        harmful |= (c > SPS) && (smin[(size_t)p * NSL + s] <= dbg + HMARG);
    }
    if (harmful) { need[p] = 2; return; }

    u64 best = 0xFFFFFFFFFFFFFFFFull;
    int namb = 0;
    #pragma unroll
    for (int s = 0; s < NSL; ++s) {
        int c = cntg[(size_t)p * NSL + s];
        int n = c < SPS ? c : SPS;
        for (int t = 0; t < n; ++t) {
            u64 v = cand[((size_t)p * NSL + s) * SPS + t];
            if (v < best) best = v;
            float dv = __uint_as_float((u32)(v >> 32));
            namb += (dv <= dbg + HMARG) ? 1 : 0;
        }
    }

    if (namb > 1) {
        // inline np-exact rescore of the deterministic contender set
        need[p] = 1;
        const float* zr = zt32 + (size_t)p * Cc;
        const float zq = zsq[p];
        u64 bb = 0xFFFFFFFFFFFFFFFFull;
        #pragma unroll
        for (int s = 0; s < NSL; ++s) {
            int c = cntg[(size_t)p * NSL + s];
            int n = c < SPS ? c : SPS;
            for (int t = 0; t < n; ++t) {
                u64 v = cand[((size_t)p * NSL + s) * SPS + t];
                float dv = __uint_as_float((u32)(v >> 32));
                if (dv <= dbg + HMARG) {
                    int k = (int)(u32)v;
                    const float* kr = key + (size_t)k * Cc;
                    float m = 0.f;
                    for (int cc = 0; cc < Cc; ++cc)
                        m = fmaf(zr[cc], kr[cc], m);
                    float d = fmaf(-2.0f, m, zq + esq[k]);
                    u64 pk = ((u64)__float_as_uint(d) << 32) | (u32)k;
                    if (pk < bb) bb = pk;
                }
            }
        }
        best = bb;
    } else {
        need[p] = 0;
    }

    idxw[p]  = (int)(u32)best;
    dbest[p] = __uint_as_float((u32)(best >> 32));
    out[ZQV + p] = (float)(u32)best;
}

// ---------------------------------------------------------------------------
// rescore_ovf: sole writer for need==2 rows. Block b owns rows
// [b*RPB2, (b+1)*RPB2); block-parallel np-exact full scan per flagged row.
// ---------------------------------------------------------------------------
__global__ __launch_bounds__(256)
void rescore_ovf(const float* __restrict__ zt32, const float* __restrict__ key,
                 const float* __restrict__ esq, const float* __restrict__ zsq,
                 const int* __restrict__ need,
                 int* __restrict__ idxw, float* __restrict__ dbest,
                 float* __restrict__ out)
{
    __shared__ float zr_s[Cc];
    __shared__ u64 wred[4];
    const int tid = threadIdx.x;

    for (int rr = 0; rr < RPB2; ++rr) {
        const int p = blockIdx.x * RPB2 + rr;
        if (need[p] != 2) continue;          // uniform across block

        __syncthreads();                     // prior row's zr_s readers done
        zr_s[tid] = zt32[(size_t)p * Cc + tid];
        __syncthreads();
        const float zq = zsq[p];

        float a0 = 0.f, a1 = 0.f, a2 = 0.f, a3 = 0.f;
        const float* kr0 = key + (size_t)(tid +   0) * Cc;
        const float* kr1 = key + (size_t)(tid + 256) * Cc;
        const float* kr2 = key + (size_t)(tid + 512) * Cc;
        const float* kr3 = key + (size_t)(tid + 768) * Cc;
        for (int cc = 0; cc < Cc; ++cc) {
            float zv = zr_s[cc];
            a0 = fmaf(zv, kr0[cc], a0);
            a1 = fmaf(zv, kr1[cc], a1);
            a2 = fmaf(zv, kr2[cc], a2);
            a3 = fmaf(zv, kr3[cc], a3);
        }
        u64 mn = 0xFFFFFFFFFFFFFFFFull;
        float av[4] = {a0, a1, a2, a3};
        #pragma unroll
        for (int g = 0; g < 4; ++g) {
            int k = tid + 256 * g;
            float d = fmaf(-2.0f, av[g], zq + esq[k]);
            u64 pk = ((u64)__float_as_uint(d) << 32) | (u32)k;
            mn = pk < mn ? pk : mn;
        }
        #pragma unroll
        for (int m = 1; m < 64; m <<= 1) {
            u64 o = __shfl_xor(mn, m, 64);
            mn = o < mn ? o : mn;
        }
        if ((tid & 63) == 0) wred[tid >> 6] = mn;
        __syncthreads();
        if (tid == 0) {
            u64 bsel = wred[0];
            #pragma unroll
            for (int i2 = 1; i2 < 4; ++i2) bsel = wred[i2] < bsel ? wred[i2] : bsel;
            idxw[p]  = (int)(u32)bsel;
            dbest[p] = __uint_as_float((u32)(bsel >> 32));
            out[ZQV + p] = (float)(u32)bsel;
        }
    }
}

// ---------------------------------------------------------------------------
// resolve_fallback (!big): monolithic deterministic path with strided z.
// ---------------------------------------------------------------------------
__global__ __launch_bounds__(256)
void resolve_fallback(const float* __restrict__ z, const float* __restrict__ key,
                      const float* __restrict__ esq, const float* __restrict__ zsq,
                      const u64* __restrict__ cand, const int* __restrict__ cntg,
                      const float* __restrict__ smin,
                      float* __restrict__ out, int* __restrict__ idxw,
                      float* __restrict__ dbest)
{
    const int p   = blockIdx.x * 256 + threadIdx.x;
    const int b   = (p >= NLOC) ? 1 : 0;
    const int loc = p - b * NLOC;
    const float* zb = z + (size_t)b * Cc * NLOC;

    float dbg = 3.4e38f;
    #pragma unroll
    for (int s = 0; s < NSL; ++s) dbg = fminf(dbg, smin[(size_t)p * NSL + s]);
    bool harmful = false;
    #pragma unroll
    for (int s = 0; s < NSL; ++s) {
        int c = cntg[(size_t)p * NSL + s];
        harmful |= (c > SPS) && (smin[(size_t)p * NSL + s] <= dbg + HMARG);
    }

    u64 sel = 0xFFFFFFFFFFFFFFFFull;
    if (harmful) {
        for (int k = 0; k < Kc; ++k) {
            const float* kr = key + (size_t)k * Cc;
            float m = 0.f;
            for (int cc = 0; cc < Cc; ++cc)
                m = fmaf(zb[(size_t)cc * NLOC + loc], kr[cc], m);
            float d = fmaf(-2.0f, m, zsq[p] + esq[k]);
            u64 pk = ((u64)__float_as_uint(d) << 32) | (u32)k;
            if (pk < sel) sel = pk;
        }
    } else {
        u64 best = 0xFFFFFFFFFFFFFFFFull;
        int namb = 0;
        #pragma unroll
        for (int s = 0; s < NSL; ++s) {
            int c = cntg[(size_t)p * NSL + s];
            int n = c < SPS ? c : SPS;
            for (int t = 0; t < n; ++t) {
                u64 v = cand[((size_t)p * NSL + s) * SPS + t];
                if (v < best) best = v;
                float dv = __uint_as_float((u32)(v >> 32));
                namb += (dv <= dbg + HMARG) ? 1 : 0;
            }
        }
        sel = best;
        if (namb > 1) {
            u64 bb = 0xFFFFFFFFFFFFFFFFull;
            #pragma unroll
            for (int s = 0; s < NSL; ++s) {
                int c = cntg[(size_t)p * NSL + s];
                int n = c < SPS ? c : SPS;
                for (int t = 0; t < n; ++t) {
                    u64 v = cand[((size_t)p * NSL + s) * SPS + t];
                    float dv = __uint_as_float((u32)(v >> 32));
                    if (dv <= dbg + HMARG) {
                        int k = (int)(u32)v;
                        const float* kr = key + (size_t)k * Cc;
                        float m = 0.f;
                        for (int cc = 0; cc < Cc; ++cc)
                            m = fmaf(zb[(size_t)cc * NLOC + loc], kr[cc], m);
                        float d = fmaf(-2.0f, m, zsq[p] + esq[k]);
                        u64 pk = ((u64)__float_as_uint(d) << 32) | (u32)k;
                        if (pk < bb) bb = pk;
                    }
                }
            }
            sel = bb;
        }
    }
    idxw[p]  = (int)(u32)sel;
    dbest[p] = __uint_as_float((u32)(sel >> 32));
    out[ZQV + p] = (float)(u32)sel;
}

// ---------------------------------------------------------------------------
// gather: val-row gather + z_q_value write + fused dbest partial.
// ---------------------------------------------------------------------------
__global__ __launch_bounds__(256)
void gather(const float* __restrict__ val, const int* __restrict__ idxw,
            const float* __restrict__ dbest,
            float* __restrict__ out, double* __restrict__ partial)
{
    __shared__ float rowbuf[RB][261];
    __shared__ int   idx_sh[RB];
    const int tid = threadIdx.x, blk = blockIdx.x;
    const int wid = tid >> 6, l = tid & 63;
    const int p0  = blk * RB;
    const int b   = (p0 >= NLOC) ? 1 : 0;
    const int loc0 = p0 - b * NLOC;

    if (tid < RB) idx_sh[tid] = idxw[p0 + tid];

    if (tid < 64) {
        double s = (tid < RB) ? (double)dbest[p0 + tid] : 0.0;
        for (int off = 32; off > 0; off >>= 1) s += __shfl_down(s, off);
        if (tid == 0) partial[blk] = s;
    }
    __syncthreads();

    #pragma unroll
    for (int i = 0; i < RB / 4; ++i) {
        int row = wid * (RB / 4) + i;
        float4 v = *reinterpret_cast<const float4*>(val + (size_t)idx_sh[row] * Cc + l * 4);
        *reinterpret_cast<float4*>(&rowbuf[row][l * 4]) = v;
    }
    __syncthreads();

    const int nq = l & 7;
    #pragma unroll
    for (int it = 0; it < 8; ++it) {
        int cc = (l >> 3) + 8 * it + 64 * wid;
        float4 v = make_float4(rowbuf[nq * 4 + 0][cc], rowbuf[nq * 4 + 1][cc],
                               rowbuf[nq * 4 + 2][cc], rowbuf[nq * 4 + 3][cc]);
        *reinterpret_cast<float4*>(
            out + ((size_t)b * Cc + cc) * NLOC + loc0 + nq * 4) = v;
    }
}

__global__ void fin_kernel(const double* __restrict__ partial, float* __restrict__ out_loss)
{
    __shared__ double sh[256];
    double s = 0.0;
    for (int i = threadIdx.x; i < F2B; i += 256) s += partial[i];
    sh[threadIdx.x] = s;
    __syncthreads();
    for (int st = 128; st > 0; st >>= 1) {
        if (threadIdx.x < st) sh[threadIdx.x] += sh[threadIdx.x + st];
        __syncthreads();
    }
    if (threadIdx.x == 0)
        out_loss[0] = (float)(1.25 * sh[0] / (double)((long long)NTOT * Cc));
}

// ---------------------------------------------------------------------------
extern "C" void kernel_launch(void* const* d_in, const int* in_sizes, int n_in,
                              void* d_out, int out_size, void* d_ws, size_t ws_size,
                              hipStream_t stream)
{
    const float* z   = (const float*)d_in[0];
    const float* key = (const float*)d_in[1];
    const float* val = (const float*)d_in[2];
    float* out = (float*)d_out;

    u16* zf16 = (u16*)d_out;   // dead before gather overwrites

    char* w = (char*)d_ws;
    u16*    ef16    = (u16*)w;                 w += (size_t)Kc * Cc * 2;             // 512 KB
    u64*    cand    = (u64*)w;                 w += (size_t)NTOT * NSL * SPS * 8;    // 25.7 MB
    int*    cntg    = (int*)w;                 w += (size_t)NTOT * NSL * 4;          // 3.2 MB
    float*  smin    = (float*)w;               w += (size_t)NTOT * NSL * 4;          // 3.2 MB
    int*    need    = (int*)w;                 w += (size_t)NTOT * 4;
    int*    idxw    = (int*)w;                 w += (size_t)NTOT * 4;
    float*  dbest   = (float*)w;               w += (size_t)NTOT * 4;
    double* partial = (double*)w;              w += (size_t)F2B * 8;
    float*  esq     = (float*)w;               w += (size_t)Kc * 4;
    float*  zsq     = (float*)w;               w += (size_t)NTOT * 4;
    float*  zt32    = (float*)w;
    size_t  need_big = (size_t)(w - (char*)d_ws) + (size_t)NTOT * Cc * 4;
    const bool big = ws_size >= need_big;

    hipLaunchKernelGGL(prep_key, dim3((Kc * Cc + 255) / 256), dim3(256), 0, stream,
                       key, ef16, esq);
    hipLaunchKernelGGL(split_z, dim3(NTOT / 64), dim3(256), 0, stream, z, zf16,
                       big ? zt32 : (float*)nullptr, zsq);
    hipLaunchKernelGGL(screen, dim3(SBLK), dim3(256), 0, stream,
                       zf16, ef16, esq, zsq, cand, cntg, smin);
    if (big) {
        hipLaunchKernelGGL(resolve, dim3(F1B), dim3(256), 0, stream,
                           zt32, key, esq, zsq, cand, cntg, smin, need, idxw, dbest, out);
        hipLaunchKernelGGL(rescore_ovf, dim3(OVB), dim3(256), 0, stream,
                           zt32, key, esq, zsq, need, idxw, dbest, out);
    } else {
        hipLaunchKernelGGL(resolve_fallback, dim3(F1B), dim3(256), 0, stream,
                           z, key, esq, zsq, cand, cntg, smin, out, idxw, dbest);
    }
    hipLaunchKernelGGL(gather, dim3(F2B), dim3(256), 0, stream,
                       val, idxw, dbest, out, partial);
    hipLaunchKernelGGL(fin_kernel, dim3(1), dim3(256), 0, stream, partial, out + ZQV + NTOT);
}